// Round 15
// baseline (183.778 us; speedup 1.0000x reference)
//
#include <hip/hip_runtime.h>
#include <math.h>

#define Bb 128
#define Tt 1024
#define Ll 96
#define NSEG 16
#define CUT(s) (1 + ((Tt - 1) * (s)) / NSEG)

// workspace layout (floats unless noted), per batch:
#define FWD_OFF(s) (((s) - 1) * 96)                       // a_s, s = 1..NSEG-1
#define BWD_OFF(s) ((NSEG - 1 + (s) - 2) * 96)            // b_s, s = 2..NSEG
#define DKF_I(s)   (2 * (NSEG - 1) * 96 + ((s) - 1))      // int, s = 1..NSEG-1
#define DKB_I(s)   (2 * (NSEG - 1) * 96 + (NSEG - 1) + ((s) - 2)) // s = 2..NSEG
#define PS_F       (2 * (NSEG - 1) * 96 + 2 * (NSEG - 1)) // float
#define WS_STRIDE  (PS_F + 34)                            // pad

typedef float v2f __attribute__((ext_vector_type(2)));
typedef float v4f __attribute__((ext_vector_type(4)));
typedef int   v2i __attribute__((ext_vector_type(2)));

// Cross-group (lane ^ 32) sum via v_permlane32_swap (VALU pipe, not LDS).
static __device__ __forceinline__ float xadd32(float p) {
#if __has_builtin(__builtin_amdgcn_permlane32_swap)
    v2i rr = __builtin_amdgcn_permlane32_swap(__float_as_int(p),
                                              __float_as_int(p), false, false);
    return __int_as_float(rr.x) + __int_as_float(rr.y);
#else
    return p + __shfl_xor(p, 32, 64);
#endif
}

// PARALLEL-IN-TIME rank-1 segmentation (rounds 14/15). M_t = diag(w_t) E^T
// strictly positive -> Birkhoff contraction ~0.5/step; a 64-step segment
// product is rank-1 to ~1e-19:
//   P_s ~= a_s b_s^T / gamma_s,  a_s = P_s y_s (fwd, y = exp(x_{lo-1})),
//   b_s^T = 1^T P_s (bwd),  gamma_s = sum(a_s).
// log Z = sum_{s=2..S} [log(b_s . a_{s-1}) + ln2(Dkb_s + Dkf_{s-1})]
//       - sum_{s=2..S-1} [log(sum a_s) + ln2 Dkf_s]
// Round 15: NSEG 8 -> 16 (serial chain 128 -> 64 steps). At NSEG=8 the scan
// was ~50% VALU-issue / ~50% residual latency; total VALU work is invariant
// in NSEG, so more segments convert latency exposure into overlap, toward
// the ~51-60us issue floor. Per-step machinery = round 13 verbatim.
__global__ __launch_bounds__(64, 1)
void crf_scan_kernel(
    const float* __restrict__ inputs,      // (B, T, L) fp32
    const int*   __restrict__ labels_idx,  // (B, T) int32
    const float* __restrict__ trans,       // (L, L) fp32
    float*       __restrict__ ws)          // 128 x WS_STRIDE floats
{
    const int cid = blockIdx.x / Bb;       // chain id 0..2*NSEG-2
    const int b   = blockIdx.x % Bb;
    const int i   = threadIdx.x;           // 0..63

    const float* xbase = inputs + (size_t)b * Tt * Ll;
    float* wsb = ws + (size_t)b * WS_STRIDE;
    int*   wsi = reinterpret_cast<int*>(wsb);

    if (cid == 2 * (NSEG - 1)) {
        // ================= SCORES =================
        float ps = 0.f;
        const int* lb = labels_idx + b * Tt;
        #pragma unroll 4
        for (int t = i; t < Tt; t += 64) {
            int i0 = lb[t];
            ps += xbase[t * Ll + i0];
            if (t < Tt - 1) ps += trans[i0 * Ll + lb[t + 1]];
        }
        #pragma unroll
        for (int off = 32; off; off >>= 1) ps += __shfl_xor(ps, off, 64);
        if (i == 0) wsb[PS_F] = ps;
        return;
    }

    const bool fw = (cid < NSEG - 1);
    const int  s  = fw ? (cid + 1) : (cid - NSEG + 3);  // fwd 1..S-1, bwd 2..S
    const int  lo = CUT(s - 1), hi = CUT(s);            // t-range [lo, hi)

    const int g   = i >> 5;            // group: state half [48g, 48g+48)
    const int j   = i & 31;            // slot: owns cols j, j+32, j+64
    const int g48 = g * 48;
    const int cA  = j, cB = j + 32, cC = j + 64;

    __shared__ __align__(16) float buf[Ll];

#define EP24(X) \
    X(0)  X(1)  X(2)  X(3)  X(4)  X(5)  X(6)  X(7)  X(8)  X(9)  X(10) X(11) \
    X(12) X(13) X(14) X(15) X(16) X(17) X(18) X(19) X(20) X(21) X(22) X(23)

#define EDECL(p) v2f EA##p, EB##p, EC##p;

#define CHUNK(q, p0, p1) { \
        aA0 += (v2f){P##q.x, P##q.y} * EA##p0; \
        aA1 += (v2f){P##q.z, P##q.w} * EA##p1; \
        aB0 += (v2f){P##q.x, P##q.y} * EB##p0; \
        aB1 += (v2f){P##q.z, P##q.w} * EB##p1; \
        aC0 += (v2f){P##q.x, P##q.y} * EC##p0; \
        aC1 += (v2f){P##q.z, P##q.w} * EC##p1; }

#define MATVEC \
        CHUNK(0, 0, 1)   CHUNK(1, 2, 3)   CHUNK(2, 4, 5)   CHUNK(3, 6, 7)   \
        CHUNK(4, 8, 9)   CHUNK(5, 10,11)  CHUNK(6, 12,13)  CHUNK(7, 14,15)  \
        CHUNK(8, 16,17)  CHUNK(9, 18,19)  CHUNK(10,20,21)  CHUNK(11,22,23)

#define PRELOAD { const v4f* qb_ = reinterpret_cast<const v4f*>(buf) + g * 12; \
        P0 = qb_[0]; P1 = qb_[1]; P2  = qb_[2];  P3  = qb_[3];  \
        P4 = qb_[4]; P5 = qb_[5]; P6  = qb_[6];  P7  = qb_[7];  \
        P8 = qb_[8]; P9 = qb_[9]; P10 = qb_[10]; P11 = qb_[11]; \
        Pk = buf[0]; }

    v4f P0,P1,P2,P3,P4,P5,P6,P7,P8,P9,P10,P11;
    float Pk;

    if (fw) {
        // ============ FORWARD chain: a_s = P_s y, y = exp(x_{lo-1}) ========
        EP24(EDECL)
#define EINIT(p) { \
        int e0 = (g48 + 2*(p)) * Ll, e1 = (g48 + 2*(p) + 1) * Ll; \
        EA##p = (v2f){__expf(trans[e0 + cA]), __expf(trans[e1 + cA])}; \
        EB##p = (v2f){__expf(trans[e0 + cB]), __expf(trans[e1 + cB])}; \
        EC##p = (v2f){__expf(trans[e0 + cC]), __expf(trans[e1 + cC])}; \
        asm volatile("" ::: "memory"); }
        EP24(EINIT)
#undef EINIT

        float qA = __expf(xbase[(lo - 1) * Ll + cA]);
        float qB = __expf(xbase[(lo - 1) * Ll + cB]);
        float qC = __expf(xbase[(lo - 1) * Ll + cC]);
        if (i < 32) { buf[cA] = qA; buf[cB] = qB; buf[cC] = qC; }
        asm volatile("" ::: "memory");
        PRELOAD

        float ewA = __expf(xbase[lo * Ll + cA]);
        float ewB = __expf(xbase[lo * Ll + cB]);
        float ewC = __expf(xbase[lo * Ll + cC]);
#define ROWF(d) ((lo + (d) > Tt - 1) ? (Tt - 1) : (lo + (d)))
        float x2A = xbase[ROWF(1)*Ll+cA], x2B = xbase[ROWF(1)*Ll+cB], x2C = xbase[ROWF(1)*Ll+cC];
        float x3A = xbase[ROWF(2)*Ll+cA], x3B = xbase[ROWF(2)*Ll+cB], x3C = xbase[ROWF(2)*Ll+cC];
        float x4A = xbase[ROWF(3)*Ll+cA], x4B = xbase[ROWF(3)*Ll+cB], x4C = xbase[ROWF(3)*Ll+cC];
        float x5A = xbase[ROWF(4)*Ll+cA], x5B = xbase[ROWF(4)*Ll+cB], x5C = xbase[ROWF(4)*Ll+cC];
        float x6A = xbase[ROWF(5)*Ll+cA], x6B = xbase[ROWF(5)*Ll+cB], x6C = xbase[ROWF(5)*Ll+cC];
        float x7A = xbase[ROWF(6)*Ll+cA], x7B = xbase[ROWF(6)*Ll+cB], x7C = xbase[ROWF(6)*Ll+cC];
#undef ROWF

        int Dk = 0;
        #pragma unroll 1
        for (int t = lo; t < hi; ++t) {
            int k = ((__float_as_int(Pk) >> 23) & 0xff) - 127;
            Dk += k;
            float r = __uint_as_float((unsigned)(127 - k) << 23); // exact 2^-k
            float wA = ewA * r, wB = ewB * r, wC = ewC * r;

            v2f aA0 = {0.f,0.f}, aA1 = {0.f,0.f};
            v2f aB0 = {0.f,0.f}, aB1 = {0.f,0.f};
            v2f aC0 = {0.f,0.f}, aC1 = {0.f,0.f};
            MATVEC
            v2f tA = aA0 + aA1, tB = aB0 + aB1, tC = aC0 + aC1;
            qA = xadd32(tA.x + tA.y) * wA;
            qB = xadd32(tB.x + tB.y) * wB;
            qC = xadd32(tC.x + tC.y) * wC;

            if (i < 32) { buf[cA] = qA; buf[cB] = qB; buf[cC] = qC; }
            asm volatile("" ::: "memory");
            PRELOAD

            ewA = __expf(x2A); ewB = __expf(x2B); ewC = __expf(x2C);
            x2A = x3A; x2B = x3B; x2C = x3C;
            x3A = x4A; x3B = x4B; x3C = x4C;
            x4A = x5A; x4B = x5B; x4C = x5C;
            x5A = x6A; x5B = x6B; x5C = x6C;
            x6A = x7A; x6B = x7B; x6C = x7C;
            int row = t + 7; if (row > Tt - 1) row = Tt - 1;
            x7A = xbase[row*Ll+cA]; x7B = xbase[row*Ll+cB]; x7C = xbase[row*Ll+cC];
        }
        if (i < 32) {
            float* dst = wsb + FWD_OFF(s);
            dst[cA] = qA; dst[cB] = qB; dst[cC] = qC;
        }
        if (i == 0) wsi[DKF_I(s)] = Dk;
    } else {
        // ============ BACKWARD chain: b_s^T = 1^T P_s ======================
        EP24(EDECL)
#define EINIT(p) { \
        v2f rA = *reinterpret_cast<const v2f*>(&trans[cA * Ll + g48 + 2*(p)]); \
        v2f rB = *reinterpret_cast<const v2f*>(&trans[cB * Ll + g48 + 2*(p)]); \
        v2f rC = *reinterpret_cast<const v2f*>(&trans[cC * Ll + g48 + 2*(p)]); \
        EA##p = (v2f){__expf(rA.x), __expf(rA.y)}; \
        EB##p = (v2f){__expf(rB.x), __expf(rB.y)}; \
        EC##p = (v2f){__expf(rC.x), __expf(rC.y)}; \
        asm volatile("" ::: "memory"); }
        EP24(EINIT)
#undef EINIT

        // s_{hi-1} = exp(x_{hi-1})
        float sA = __expf(xbase[(hi-1)*Ll + cA]);
        float sB = __expf(xbase[(hi-1)*Ll + cB]);
        float sC = __expf(xbase[(hi-1)*Ll + cC]);
        if (i < 32) { buf[cA] = sA; buf[cB] = sB; buf[cC] = sC; }
        asm volatile("" ::: "memory");
        PRELOAD

        float ewA = __expf(xbase[(hi-2)*Ll + cA]);
        float ewB = __expf(xbase[(hi-2)*Ll + cB]);
        float ewC = __expf(xbase[(hi-2)*Ll + cC]);
#define ROWB(d) ((hi - (d) < 0) ? 0 : (hi - (d)))
        float x2A = xbase[ROWB(3)*Ll+cA], x2B = xbase[ROWB(3)*Ll+cB], x2C = xbase[ROWB(3)*Ll+cC];
        float x3A = xbase[ROWB(4)*Ll+cA], x3B = xbase[ROWB(4)*Ll+cB], x3C = xbase[ROWB(4)*Ll+cC];
        float x4A = xbase[ROWB(5)*Ll+cA], x4B = xbase[ROWB(5)*Ll+cB], x4C = xbase[ROWB(5)*Ll+cC];
        float x5A = xbase[ROWB(6)*Ll+cA], x5B = xbase[ROWB(6)*Ll+cB], x5C = xbase[ROWB(6)*Ll+cC];
        float x6A = xbase[ROWB(7)*Ll+cA], x6B = xbase[ROWB(7)*Ll+cB], x6C = xbase[ROWB(7)*Ll+cC];
        float x7A = xbase[ROWB(8)*Ll+cA], x7B = xbase[ROWB(8)*Ll+cB], x7C = xbase[ROWB(8)*Ll+cC];
#undef ROWB

        int Dk = 0, k = 0;
        float VA = 0.f, VB = 0.f, VC = 0.f;
        #pragma unroll 1
        for (int t = hi - 1; t >= lo; --t) {
            k = ((__float_as_int(Pk) >> 23) & 0xff) - 127;
            Dk += k;
            float r = __uint_as_float((unsigned)(127 - k) << 23);

            v2f aA0 = {0.f,0.f}, aA1 = {0.f,0.f};
            v2f aB0 = {0.f,0.f}, aB1 = {0.f,0.f};
            v2f aC0 = {0.f,0.f}, aC1 = {0.f,0.f};
            MATVEC
            v2f tA = aA0 + aA1, tB = aB0 + aB1, tC = aC0 + aC1;
            VA = xadd32(tA.x + tA.y);       // v_{t-1} (stored scale)
            VB = xadd32(tB.x + tB.y);
            VC = xadd32(tC.x + tC.y);

            float swA = VA * (ewA * r);     // s_{t-1}
            float swB = VB * (ewB * r);
            float swC = VC * (ewC * r);
            if (i < 32) { buf[cA] = swA; buf[cB] = swB; buf[cC] = swC; }
            asm volatile("" ::: "memory");
            PRELOAD

            ewA = __expf(x2A); ewB = __expf(x2B); ewC = __expf(x2C);
            x2A = x3A; x2B = x3B; x2C = x3C;
            x3A = x4A; x3B = x4B; x3C = x4C;
            x4A = x5A; x4B = x5B; x4C = x5C;
            x5A = x6A; x5B = x6B; x5C = x6C;
            x6A = x7A; x6B = x7B; x6C = x7C;
            int row = t - 8; if (row < 0) row = 0;
            x7A = xbase[row*Ll+cA]; x7B = xbase[row*Ll+cB]; x7C = xbase[row*Ll+cC];
        }
        Dk -= k;   // last k applied only to the never-consumed s_{lo-1} write
        if (i < 32) {
            float* dst = wsb + BWD_OFF(s);
            dst[cA] = VA; dst[cB] = VB; dst[cC] = VC;
        }
        if (i == 0) wsi[DKB_I(s)] = Dk;
    }
#undef PRELOAD
#undef MATVEC
#undef CHUNK
#undef EDECL
#undef EP24
}

// log Z = sum_{s=2..S} [log(b_s . a_{s-1}) + ln2(Dkb_s + Dkf_{s-1})]
//       - sum_{s=2..S-1} [log(sum a_s) + ln2 Dkf_s];  out = log Z - ps
__global__ __launch_bounds__(64, 1) void crf_combine_kernel(
    const float* __restrict__ ws, float* __restrict__ out)
{
    const int b = blockIdx.x;
    const int i = threadIdx.x;
    const float* wsb = ws + (size_t)b * WS_STRIDE;
    const int*   wsi = reinterpret_cast<const int*>(wsb);
    const double LN2 = 0.6931471805599453;

    double acc = 0.0;
    #pragma unroll 1
    for (int s = 2; s <= NSEG; ++s) {
        const float* f  = wsb + FWD_OFF(s - 1);
        const float* bv = wsb + BWD_OFF(s);
        float pd = 0.f;
        if (i < 32) pd = bv[i]*f[i] + bv[i+32]*f[i+32] + bv[i+64]*f[i+64];
        #pragma unroll
        for (int off = 32; off; off >>= 1) pd += __shfl_xor(pd, off, 64);
        acc += log((double)pd)
             + LN2 * (double)(wsi[DKB_I(s)] + wsi[DKF_I(s - 1)]);
    }
    #pragma unroll 1
    for (int s = 2; s <= NSEG - 1; ++s) {
        const float* f = wsb + FWD_OFF(s);
        float pg = 0.f;
        if (i < 32) pg = f[i] + f[i+32] + f[i+64];
        #pragma unroll
        for (int off = 32; off; off >>= 1) pg += __shfl_xor(pg, off, 64);
        acc -= log((double)pg) + LN2 * (double)wsi[DKF_I(s)];
    }
    if (i == 0) out[b] = (float)(acc - (double)wsb[PS_F]);
}

extern "C" void kernel_launch(void* const* d_in, const int* in_sizes, int n_in,
                              void* d_out, int out_size, void* d_ws, size_t ws_size,
                              hipStream_t stream) {
    const float* inputs     = (const float*)d_in[0];
    const int*   labels_idx = (const int*)d_in[1];
    const float* trans      = (const float*)d_in[2];
    float*       out        = (float*)d_out;
    float*       ws         = (float*)d_ws;

    crf_scan_kernel<<<dim3((2 * NSEG - 1) * Bb), dim3(64), 0, stream>>>(
        inputs, labels_idx, trans, ws);
    crf_combine_kernel<<<dim3(Bb), dim3(64), 0, stream>>>(ws, out);
}

// Round 16
// 147.094 us; speedup vs baseline: 1.2494x; 1.2494x over previous
//
#include <hip/hip_runtime.h>
#include <math.h>

#define Bb 128
#define Tt 1024
#define Ll 96
#define NSEG 16
#define DELTA 24
#define CUT(s) (1 + ((Tt - 1) * (s)) / NSEG)

// ws per batch: [0..N) end_sum (f32); [N..2N) junc_sum; [2N..3N) end_dk (i32);
// [3N..4N) junc_dk; [4N] ps.
#define WS_STRIDE 80

typedef float v2f __attribute__((ext_vector_type(2)));
typedef float v4f __attribute__((ext_vector_type(4)));
typedef int   v2i __attribute__((ext_vector_type(2)));

// Cross-group (lane ^ 32) sum via v_permlane32_swap (VALU pipe, not LDS).
static __device__ __forceinline__ float xadd32(float p) {
#if __has_builtin(__builtin_amdgcn_permlane32_swap)
    v2i rr = __builtin_amdgcn_permlane32_swap(__float_as_int(p),
                                              __float_as_int(p), false, false);
    return __int_as_float(rr.x) + __int_as_float(rr.y);
#else
    return p + __shfl_xor(p, 32, 64);
#endif
}

// FORWARD-ONLY overlapped chains (round 16). Rounds 14/15 (fwd+bwd rank-1)
// were throughput-bound on combined VALU+LDS pipe demand (NSEG 8->16 flat at
// ~105us, VALUBusy ~54%): total work 2T is the binding quantity. This scheme
// does T + (S-1)*DELTA steps (0.68x): chain s warms up DELTA=24 steps before
// its segment from y = exp(x_{w-1}); Birkhoff contraction (~0.25/step ->
// 1e-15 over 24) aligns its DIRECTION with the true state, and the scale
// error telescopes via SCALARS:
//   logZ = sum_s [log(sum q at hi_s-1) + ln2*DkEnd_s]
//        - sum_{s>=2} [log(sum q at lo_s-1) + ln2*DkJunc_s]
// (chain s-1's end point IS chain s's junction point: captured twice, once
// accurately, once locally-initialized; the ratio is the scale correction.
// Reduces EXACTLY to round 6's verified formula at S=1.)
// Per-step machinery = round 13/15 forward verbatim (group-split matvec,
// 13 broadcast ds_read_b128, 72 pk-FMA, permlane32 combine, exponent-field
// rescale with integer Dk).
__global__ __launch_bounds__(64, 1)
void crf_scan_kernel(
    const float* __restrict__ inputs,      // (B, T, L) fp32
    const int*   __restrict__ labels_idx,  // (B, T) int32
    const float* __restrict__ trans,       // (L, L) fp32
    float*       __restrict__ ws)          // 128 x WS_STRIDE floats
{
    const int cid = blockIdx.x / Bb;       // 0..NSEG-1 chains, NSEG = scores
    const int b   = blockIdx.x % Bb;
    const int i   = threadIdx.x;           // 0..63

    const float* xbase = inputs + (size_t)b * Tt * Ll;
    float* wsb = ws + (size_t)b * WS_STRIDE;
    int*   wsi = reinterpret_cast<int*>(wsb);

    if (cid == NSEG) {
        // ================= SCORES =================
        float ps = 0.f;
        const int* lb = labels_idx + b * Tt;
        #pragma unroll 4
        for (int t = i; t < Tt; t += 64) {
            int i0 = lb[t];
            ps += xbase[t * Ll + i0];
            if (t < Tt - 1) ps += trans[i0 * Ll + lb[t + 1]];
        }
        #pragma unroll
        for (int off = 32; off; off >>= 1) ps += __shfl_xor(ps, off, 64);
        if (i == 0) wsb[4 * NSEG] = ps;
        return;
    }

    const int s  = cid + 1;                          // 1..NSEG
    const int lo = CUT(s - 1), hi = CUT(s);          // segment [lo, hi)
    const int w0 = (s == 1) ? 1 : ((lo - DELTA < 1) ? 1 : lo - DELTA);
    const int jt = (s == 1) ? 0 : (lo - 1);          // junction t (0 = never)

    const int g   = i >> 5;            // group: state half [48g, 48g+48)
    const int j   = i & 31;            // slot: owns cols j, j+32, j+64
    const int g48 = g * 48;
    const int cA  = j, cB = j + 32, cC = j + 64;

    __shared__ __align__(16) float buf[Ll];

#define EP24(X) \
    X(0)  X(1)  X(2)  X(3)  X(4)  X(5)  X(6)  X(7)  X(8)  X(9)  X(10) X(11) \
    X(12) X(13) X(14) X(15) X(16) X(17) X(18) X(19) X(20) X(21) X(22) X(23)

#define EDECL(p) v2f EA##p, EB##p, EC##p;
    EP24(EDECL)
#undef EDECL
    // fwd layout: EA_p = {E[2p'][cA], E[2p'+1][cA]} for own-half elems
#define EINIT(p) { \
        int e0 = (g48 + 2*(p)) * Ll, e1 = (g48 + 2*(p) + 1) * Ll; \
        EA##p = (v2f){__expf(trans[e0 + cA]), __expf(trans[e1 + cA])}; \
        EB##p = (v2f){__expf(trans[e0 + cB]), __expf(trans[e1 + cB])}; \
        EC##p = (v2f){__expf(trans[e0 + cC]), __expf(trans[e1 + cC])}; \
        asm volatile("" ::: "memory"); }
    EP24(EINIT)
#undef EINIT

#define CHUNK(q, p0, p1) { \
        aA0 += (v2f){P##q.x, P##q.y} * EA##p0; \
        aA1 += (v2f){P##q.z, P##q.w} * EA##p1; \
        aB0 += (v2f){P##q.x, P##q.y} * EB##p0; \
        aB1 += (v2f){P##q.z, P##q.w} * EB##p1; \
        aC0 += (v2f){P##q.x, P##q.y} * EC##p0; \
        aC1 += (v2f){P##q.z, P##q.w} * EC##p1; }

#define MATVEC \
        CHUNK(0, 0, 1)   CHUNK(1, 2, 3)   CHUNK(2, 4, 5)   CHUNK(3, 6, 7)   \
        CHUNK(4, 8, 9)   CHUNK(5, 10,11)  CHUNK(6, 12,13)  CHUNK(7, 14,15)  \
        CHUNK(8, 16,17)  CHUNK(9, 18,19)  CHUNK(10,20,21)  CHUNK(11,22,23)

#define PRELOAD { const v4f* qb_ = reinterpret_cast<const v4f*>(buf) + g * 12; \
        P0 = qb_[0]; P1 = qb_[1]; P2  = qb_[2];  P3  = qb_[3];  \
        P4 = qb_[4]; P5 = qb_[5]; P6  = qb_[6];  P7  = qb_[7];  \
        P8 = qb_[8]; P9 = qb_[9]; P10 = qb_[10]; P11 = qb_[11]; \
        Pk = buf[0]; }

    v4f P0,P1,P2,P3,P4,P5,P6,P7,P8,P9,P10,P11;
    float Pk;

    // init state at t0 = w0-1: q = exp(x_{t0}) (exact for s=1; warmup-seed
    // for s>1 -- any positive vector works, this one is best-conditioned)
    float qA = __expf(xbase[(w0 - 1) * Ll + cA]);
    float qB = __expf(xbase[(w0 - 1) * Ll + cB]);
    float qC = __expf(xbase[(w0 - 1) * Ll + cC]);
    if (i < 32) { buf[cA] = qA; buf[cB] = qB; buf[cC] = qC; }
    asm volatile("" ::: "memory");
    PRELOAD

    float ewA = __expf(xbase[w0 * Ll + cA]);
    float ewB = __expf(xbase[w0 * Ll + cB]);
    float ewC = __expf(xbase[w0 * Ll + cC]);
#define ROWF(d) ((w0 + (d) > Tt - 1) ? (Tt - 1) : (w0 + (d)))
    float x2A = xbase[ROWF(1)*Ll+cA], x2B = xbase[ROWF(1)*Ll+cB], x2C = xbase[ROWF(1)*Ll+cC];
    float x3A = xbase[ROWF(2)*Ll+cA], x3B = xbase[ROWF(2)*Ll+cB], x3C = xbase[ROWF(2)*Ll+cC];
    float x4A = xbase[ROWF(3)*Ll+cA], x4B = xbase[ROWF(3)*Ll+cB], x4C = xbase[ROWF(3)*Ll+cC];
    float x5A = xbase[ROWF(4)*Ll+cA], x5B = xbase[ROWF(4)*Ll+cB], x5C = xbase[ROWF(4)*Ll+cC];
    float x6A = xbase[ROWF(5)*Ll+cA], x6B = xbase[ROWF(5)*Ll+cB], x6C = xbase[ROWF(5)*Ll+cC];
    float x7A = xbase[ROWF(6)*Ll+cA], x7B = xbase[ROWF(6)*Ll+cB], x7C = xbase[ROWF(6)*Ll+cC];
#undef ROWF

    int Dk = 0;
    float jsum = 1.f; int jdk = 0;      // junction capture
    #pragma unroll 1
    for (int t = w0; t < hi; ++t) {
        int k = ((__float_as_int(Pk) >> 23) & 0xff) - 127;  // wave-uniform
        Dk += k;
        float r = __uint_as_float((unsigned)(127 - k) << 23); // exact 2^-k
        float wA = ewA * r, wB = ewB * r, wC = ewC * r;

        v2f aA0 = {0.f,0.f}, aA1 = {0.f,0.f};
        v2f aB0 = {0.f,0.f}, aB1 = {0.f,0.f};
        v2f aC0 = {0.f,0.f}, aC1 = {0.f,0.f};
        MATVEC
        v2f tA = aA0 + aA1, tB = aB0 + aB1, tC = aC0 + aC1;
        qA = xadd32(tA.x + tA.y) * wA;
        qB = xadd32(tB.x + tB.y) * wB;
        qC = xadd32(tC.x + tC.y) * wC;

        if (i < 32) { buf[cA] = qA; buf[cB] = qB; buf[cC] = qC; }
        asm volatile("" ::: "memory");
        PRELOAD

        // junction capture (wave-uniform branch; taken once per chain)
        if (t == jt) {
            float ssum = qA + qB + qC;
            #pragma unroll
            for (int off = 16; off; off >>= 1) ssum += __shfl_xor(ssum, off, 64);
            jsum = ssum; jdk = Dk;
        }

        // off-path bookkeeping (overlaps the read-train latency)
        ewA = __expf(x2A); ewB = __expf(x2B); ewC = __expf(x2C);
        x2A = x3A; x2B = x3B; x2C = x3C;
        x3A = x4A; x3B = x4B; x3C = x4C;
        x4A = x5A; x4B = x5B; x4C = x5C;
        x5A = x6A; x5B = x6B; x5C = x6C;
        x6A = x7A; x6B = x7B; x6C = x7C;
        int row = t + 7; if (row > Tt - 1) row = Tt - 1;
        x7A = xbase[row*Ll+cA]; x7B = xbase[row*Ll+cB]; x7C = xbase[row*Ll+cC];
    }

    // end capture at t = hi-1
    float esum = qA + qB + qC;
    #pragma unroll
    for (int off = 16; off; off >>= 1) esum += __shfl_xor(esum, off, 64);

    if (i == 0) {
        wsb[s - 1]            = esum;
        wsb[NSEG + s - 1]     = jsum;
        wsi[2 * NSEG + s - 1] = Dk;
        wsi[3 * NSEG + s - 1] = jdk;
    }
#undef PRELOAD
#undef MATVEC
#undef CHUNK
#undef EP24
}

// logZ = sum_s [log(end_s) + ln2 DkEnd_s] - sum_{s>=2} [log(junc_s) + ln2 DkJunc_s]
__global__ __launch_bounds__(64, 1) void crf_combine_kernel(
    const float* __restrict__ ws, float* __restrict__ out)
{
    const int b = blockIdx.x;
    if (threadIdx.x != 0) return;
    const float* wsb = ws + (size_t)b * WS_STRIDE;
    const int*   wsi = reinterpret_cast<const int*>(wsb);
    const double LN2 = 0.6931471805599453;

    double acc = 0.0;
    #pragma unroll 1
    for (int s = 1; s <= NSEG; ++s) {
        acc += log((double)wsb[s - 1]) + LN2 * (double)wsi[2 * NSEG + s - 1];
        if (s >= 2)
            acc -= log((double)wsb[NSEG + s - 1]) + LN2 * (double)wsi[3 * NSEG + s - 1];
    }
    out[b] = (float)(acc - (double)wsb[4 * NSEG]);
}

extern "C" void kernel_launch(void* const* d_in, const int* in_sizes, int n_in,
                              void* d_out, int out_size, void* d_ws, size_t ws_size,
                              hipStream_t stream) {
    const float* inputs     = (const float*)d_in[0];
    const int*   labels_idx = (const int*)d_in[1];
    const float* trans      = (const float*)d_in[2];
    float*       out        = (float*)d_out;
    float*       ws         = (float*)d_ws;

    crf_scan_kernel<<<dim3((NSEG + 1) * Bb), dim3(64), 0, stream>>>(
        inputs, labels_idx, trans, ws);
    crf_combine_kernel<<<dim3(Bb), dim3(64), 0, stream>>>(ws, out);
}